// Round 1
// baseline (806.312 us; speedup 1.0000x reference)
//
#include <hip/hip_runtime.h>

// LocalizeAttention: out[b,h,n,f,c] = x[b,h, n_shifted(n,f), c] or 0 at the
// zero-padded volume boundary. H=W=D=24, N=13824, d=32, filters=27.
// Pure memory-streaming gather: write-BW bound (764 MB out, 28 MB in).

typedef float v4f __attribute__((ext_vector_type(4)));

constexpr int H = 24, W = 24, D = 24;
constexpr int N = H * W * D;   // 13824
constexpr int FN = 27;

__global__ __launch_bounds__(256) void localize_kernel(
    const v4f* __restrict__ x4, v4f* __restrict__ out4, int n4_total) {
  int idx = blockIdx.x * 256 + threadIdx.x;
  if (idx >= n4_total) return;

  // idx = (((bh*N + n)*27 + f) * 8 + c4)   (8 float4 per 32-float row)
  int c4 = idx & 7;
  int t  = idx >> 3;          // (bh*N + n)*27 + f
  int f  = t % FN;            // const-divisor -> magic mul
  int t2 = t / FN;            // bh*N + n
  int n  = t2 % N;            // position within the volume

  int ii  = n / (W * D);
  int rem = n % (W * D);
  int jj  = rem / D;
  int kk  = rem % D;

  int di = f / 9 - 1;
  int dj = (f / 3) % 3 - 1;
  int dk = f % 3 - 1;

  int si = ii + di, sj = jj + dj, sk = kk + dk;

  v4f v = (v4f)(0.0f);
  if ((unsigned)si < (unsigned)H && (unsigned)sj < (unsigned)W &&
      (unsigned)sk < (unsigned)D) {
    int delta = di * (W * D) + dj * D + dk;   // shift in flattened n
    v = x4[(t2 + delta) * 8 + c4];            // bh offset folds into t2
  }
  // Non-temporal: 764 MB write stream should not evict the 28 MB input
  // from L2/LLC (input is logically re-read 27x).
  __builtin_nontemporal_store(v, &out4[idx]);
}

extern "C" void kernel_launch(void* const* d_in, const int* in_sizes, int n_in,
                              void* d_out, int out_size, void* d_ws, size_t ws_size,
                              hipStream_t stream) {
  const v4f* x4 = (const v4f*)d_in[0];
  v4f* out4 = (v4f*)d_out;
  int n4 = out_size / 4;                 // 47,775,744 float4s
  int blocks = (n4 + 255) / 256;
  localize_kernel<<<blocks, 256, 0, stream>>>(x4, out4, n4);
}